// Round 5
// baseline (430.601 us; speedup 1.0000x reference)
//
#include <hip/hip_runtime.h>
#include <hip/hip_bf16.h>

#define NB  16
#define NN  16384
#define NC  256
#define NPP 128
#define NSS 16

#define FTH 512   // fps threads per block (8 waves)
#define QPT 16    // float4 quads per thread (= 32 points)

// ---------------- weight transpose (one-shot, tiny) ----------------
__global__ __launch_bounds__(256) void transpose_kernel(
    const float* __restrict__ W1, const float* __restrict__ W2,
    const float* __restrict__ W3, const float* __restrict__ Wm,
    float* __restrict__ W1T, float* __restrict__ W2T,
    float* __restrict__ W3T, float* __restrict__ WmT) {
  int i = blockIdx.x * 256 + threadIdx.x;
  if (i < 128 * 259) { int o = i / 259, c = i - o * 259; W1T[c * 128 + o] = W1[i]; }
  if (i < 128 * 128) {
    int o = i >> 7, c = i & 127;
    W2T[c * 128 + o] = W2[i];
    W3T[c * 128 + o] = W3[i];
    WmT[c * 128 + o] = Wm[i];
    WmT[16384 + c * 128 + o] = Wm[16384 + i];
  }
}

// ---------------- FPS: one block per batch ----------------
// Exact numpy semantics: d = ((dx*dx + dy*dy) + dz*dz), per-op rounding,
// argmax tie-break = lowest index via packed u64 max:
//   pack = (f32bits(val) << 32) | (0xFFFFFFFF - idx)
// Design: x,y live in LDS as float4 pairs (8192*16B = 128 KB) and are
// re-read每 iteration via ds_read_b128 (~1536 cyc/CU/iter, overlaps VALU);
// z + min-dist stay in registers (~64 regs -> no spill, compiler-friendly).
// This removes the compiler's load-sinking freedom that made rounds 2-4
// L2/scratch-bound (1.8 us/iter); now ~0.65 us/iter compute floor.
__global__ __launch_bounds__(FTH, 2) void fps_kernel(
    const float* __restrict__ xyz, int* __restrict__ fps_ws,
    float* __restrict__ centers, float* __restrict__ out_xyz,
    float* __restrict__ out_indf) {
  int b = blockIdx.x;
  const float* px = xyz + (size_t)b * (NN * 3);
  int t = threadIdx.x;
  __shared__ float4 sxy[NN / 2];              // 128 KB: (x0,y0,x1,y1) pairs
  __shared__ unsigned long long cand[2][8];
  float Zr[2 * QPT], MD[2 * QPT];
#pragma unroll
  for (int q = 0; q < QPT; ++q) {
    int pq = t + q * FTH;          // quad index
    int n0 = pq * 2;               // first point of pair
    const float* p = px + n0 * 3;
    float x0 = p[0], y0 = p[1], z0 = p[2];
    float x1 = p[3], y1 = p[4], z1 = p[5];
    asm volatile("" : "+v"(z0), "+v"(z1));  // keep z in regs, not re-loaded
    sxy[pq] = make_float4(x0, y0, x1, y1);
    Zr[2 * q] = z0; Zr[2 * q + 1] = z1;
    MD[2 * q] = 1e10f; MD[2 * q + 1] = 1e10f;
  }
  float cx = px[0], cy = px[1], cz = px[2];
  if (t == 0) {
    fps_ws[b * NPP] = 0;
    out_indf[b * NPP] = 0.0f;
    centers[(b * NPP) * 3 + 0] = cx;
    centers[(b * NPP) * 3 + 1] = cy;
    centers[(b * NPP) * 3 + 2] = cz;
    out_xyz[(b * NPP) * 3 + 0] = cx;
    out_xyz[(b * NPP) * 3 + 1] = cy;
    out_xyz[(b * NPP) * 3 + 2] = cz;
  }
  __syncthreads();
  for (int it = 1; it < NPP; ++it) {
    float bv = -1.0f;
    int bi = 0;
#pragma unroll
    for (int q = 0; q < QPT; ++q) {
      int pq = t + q * FTH;
      float4 v = sxy[pq];
      int n0 = pq * 2;
      {
        float dx = __fsub_rn(v.x, cx);
        float dy = __fsub_rn(v.y, cy);
        float dz = __fsub_rn(Zr[2 * q], cz);
        float d  = __fadd_rn(__fadd_rn(__fmul_rn(dx, dx), __fmul_rn(dy, dy)),
                             __fmul_rn(dz, dz));
        float m = fminf(MD[2 * q], d);
        MD[2 * q] = m;
        if (m > bv) { bv = m; bi = n0; }
      }
      {
        float dx = __fsub_rn(v.z, cx);
        float dy = __fsub_rn(v.w, cy);
        float dz = __fsub_rn(Zr[2 * q + 1], cz);
        float d  = __fadd_rn(__fadd_rn(__fmul_rn(dx, dx), __fmul_rn(dy, dy)),
                             __fmul_rn(dz, dz));
        float m = fminf(MD[2 * q + 1], d);
        MD[2 * q + 1] = m;
        if (m > bv) { bv = m; bi = n0 + 1; }
      }
    }
    unsigned long long pk =
        (((unsigned long long)__float_as_uint(bv)) << 32) |
        (unsigned long long)(0xFFFFFFFFu - (unsigned)bi);
#pragma unroll
    for (int off = 1; off < 64; off <<= 1) {
      unsigned long long o = __shfl_xor(pk, off, 64);
      if (o > pk) pk = o;
    }
    if ((t & 63) == 0) cand[it & 1][t >> 6] = pk;
    __syncthreads();
    const unsigned long long* cp = cand[it & 1];
    unsigned long long mx = cp[0];
#pragma unroll
    for (int w = 1; w < 8; ++w) {
      unsigned long long v = cp[w];
      if (v > mx) mx = v;
    }
    int win = (int)(0xFFFFFFFFu - (unsigned)(mx & 0xFFFFFFFFull));
    win = __builtin_amdgcn_readfirstlane(win);
    float4 qv = sxy[win >> 1];                 // uniform LDS read (broadcast)
    cx = (win & 1) ? qv.z : qv.x;
    cy = (win & 1) ? qv.w : qv.y;
    cz = px[win * 3 + 2];                      // uniform global (L2)
    if (t == 0) {
      fps_ws[b * NPP + it] = win;
      out_indf[b * NPP + it] = (float)win;
      centers[(b * NPP + it) * 3 + 0] = cx;
      centers[(b * NPP + it) * 3 + 1] = cy;
      centers[(b * NPP + it) * 3 + 2] = cz;
      out_xyz[(b * NPP + it) * 3 + 0] = cx;
      out_xyz[(b * NPP + it) * 3 + 1] = cy;
      out_xyz[(b * NPP + it) * 3 + 2] = cz;
    }
  }
}

// ---------------- ball query: one wave per (b, center) ----------------
__global__ __launch_bounds__(64) void ballq_kernel(
    const float* __restrict__ xyz, const float* __restrict__ centers,
    int* __restrict__ bidx) {
  int bs = blockIdx.x;  // b*128 + s
  int b = bs >> 7;
  int lane = threadIdx.x;
  const float* px = xyz + (size_t)b * (NN * 3);
  float cx = centers[bs * 3 + 0];
  float cy = centers[bs * 3 + 1];
  float cz = centers[bs * 3 + 2];
  __shared__ int coll[NSS];
  const float rr = 0.09f;  // f32(0.09): identical membership to f64 compare
  int have = 0;
  for (int c0 = 0; c0 < NN; c0 += 64) {
    int n = c0 + lane;
    float dx = __fsub_rn(px[n * 3 + 0], cx);
    float dy = __fsub_rn(px[n * 3 + 1], cy);
    float dz = __fsub_rn(px[n * 3 + 2], cz);
    float d2 = __fadd_rn(__fadd_rn(__fmul_rn(dx, dx), __fmul_rn(dy, dy)),
                         __fmul_rn(dz, dz));
    bool in = d2 < rr;
    unsigned long long m = __ballot(in);
    if (in) {
      int pos = have + __popcll(m & ((1ull << lane) - 1ull));
      if (pos < NSS) coll[pos] = n;
    }
    have += __popcll(m);
    if (have >= NSS) break;
  }
  __syncthreads();
  int first = coll[0];
  if (lane < NSS) bidx[bs * NSS + lane] = (lane < have) ? coll[lane] : first;
}

// ---------------- grouped MLP (3 layers + maxpool over NS) ----------------
__device__ __forceinline__ void layer_f(const float (*in)[20], int cin,
                                        const float* __restrict__ WT,
                                        const float* __restrict__ sc,
                                        const float* __restrict__ bi,
                                        int o2, int k0, float4& r0, float4& r1) {
  float a0[4] = {0.f, 0.f, 0.f, 0.f};
  float a1[4] = {0.f, 0.f, 0.f, 0.f};
  for (int c = 0; c < cin; ++c) {
    float2 w = *(const float2*)(WT + c * 128 + o2);
    float4 gv = *(const float4*)(&in[c][k0]);
    a0[0] = fmaf(w.x, gv.x, a0[0]);
    a0[1] = fmaf(w.x, gv.y, a0[1]);
    a0[2] = fmaf(w.x, gv.z, a0[2]);
    a0[3] = fmaf(w.x, gv.w, a0[3]);
    a1[0] = fmaf(w.y, gv.x, a1[0]);
    a1[1] = fmaf(w.y, gv.y, a1[1]);
    a1[2] = fmaf(w.y, gv.z, a1[2]);
    a1[3] = fmaf(w.y, gv.w, a1[3]);
  }
  float s0 = sc[o2], s1 = sc[o2 + 1], b0 = bi[o2], b1 = bi[o2 + 1];
  r0.x = fmaxf(fmaf(a0[0], s0, b0), 0.f);
  r0.y = fmaxf(fmaf(a0[1], s0, b0), 0.f);
  r0.z = fmaxf(fmaf(a0[2], s0, b0), 0.f);
  r0.w = fmaxf(fmaf(a0[3], s0, b0), 0.f);
  r1.x = fmaxf(fmaf(a1[0], s1, b1), 0.f);
  r1.y = fmaxf(fmaf(a1[1], s1, b1), 0.f);
  r1.z = fmaxf(fmaf(a1[2], s1, b1), 0.f);
  r1.w = fmaxf(fmaf(a1[3], s1, b1), 0.f);
}

__global__ __launch_bounds__(256) void mlp_kernel(
    const float* __restrict__ xyz, const float* __restrict__ feats,
    const float* __restrict__ centers, const int* __restrict__ bidx,
    const float* __restrict__ W1T, const float* __restrict__ W2T,
    const float* __restrict__ W3T, const float* __restrict__ sa_sc,
    const float* __restrict__ sa_bi, float* __restrict__ feat0) {
  int bs = blockIdx.x;
  int b = bs >> 7;
  int s = bs & 127;
  int tid = threadIdx.x;
  __shared__ float g[259][20];
  __shared__ float h1[128][20];
  __shared__ float h2[128][20];
  __shared__ int kidx[NSS];
  __shared__ float ctr[3];
  if (tid < NSS) kidx[tid] = bidx[bs * NSS + tid];
  if (tid < 3) ctr[tid] = centers[bs * 3 + tid];
  __syncthreads();
  const float* px = xyz + (size_t)b * (NN * 3);
  if (tid < NSS) {
    int n = kidx[tid];
    g[0][tid] = __fdiv_rn(__fsub_rn(px[n * 3 + 0], ctr[0]), 0.3f);
    g[1][tid] = __fdiv_rn(__fsub_rn(px[n * 3 + 1], ctr[1]), 0.3f);
    g[2][tid] = __fdiv_rn(__fsub_rn(px[n * 3 + 2], ctr[2]), 0.3f);
  }
  {
    const float* row = feats + ((size_t)b * NC + tid) * NN;
#pragma unroll
    for (int k = 0; k < NSS; ++k) g[3 + tid][k] = row[kidx[k]];
  }
  __syncthreads();
  int o2 = (tid & 63) * 2;
  int k0 = (tid >> 6) * 4;
  float4 r0, r1;
  layer_f(g, 259, W1T, sa_sc, sa_bi, o2, k0, r0, r1);
  *(float4*)&h1[o2][k0] = r0;
  *(float4*)&h1[o2 + 1][k0] = r1;
  __syncthreads();
  layer_f(h1, 128, W2T, sa_sc + 128, sa_bi + 128, o2, k0, r0, r1);
  *(float4*)&h2[o2][k0] = r0;
  *(float4*)&h2[o2 + 1][k0] = r1;
  __syncthreads();
  layer_f(h2, 128, W3T, sa_sc + 256, sa_bi + 256, o2, k0, r0, r1);
  float m0 = fmaxf(fmaxf(r0.x, r0.y), fmaxf(r0.z, r0.w));
  float m1 = fmaxf(fmaxf(r1.x, r1.y), fmaxf(r1.z, r1.w));
  int w = tid >> 6;
  h1[o2][w] = m0;
  h1[o2 + 1][w] = m1;
  __syncthreads();
  if (tid < 128) {
    float m = fmaxf(fmaxf(h1[tid][0], h1[tid][1]), fmaxf(h1[tid][2], h1[tid][3]));
    feat0[((size_t)b * 128 + tid) * 128 + s] = m;
  }
}

// ---------------- FC heads: (x@Wm + bm)*scale + bias, relu, x2 ----------------
__global__ __launch_bounds__(256) void head_kernel(
    const float* __restrict__ feat0, const float* __restrict__ WmT,
    const float* __restrict__ bm, const float* __restrict__ msc,
    const float* __restrict__ mbi, float* __restrict__ out_feat) {
  int blk = blockIdx.x;
  int b = blk >> 2;
  int sbase = (blk & 3) * 32;
  int tid = threadIdx.x;
  __shared__ float fa[128][36];
  __shared__ float fb[128][36];
  {
    int sj = tid & 31, c0 = tid >> 5;
    for (int c = c0; c < 128; c += 8)
      fa[c][sj] = feat0[((size_t)b * 128 + c) * 128 + sbase + sj];
  }
  __syncthreads();
  int o2 = (tid & 63) * 2, s0 = (tid >> 6) * 8;
  float a0[8], a1[8];
#pragma unroll
  for (int j = 0; j < 8; ++j) { a0[j] = 0.f; a1[j] = 0.f; }
  for (int c = 0; c < 128; ++c) {
    float2 w = *(const float2*)&WmT[c * 128 + o2];
    float4 f0 = *(const float4*)&fa[c][s0];
    float4 f1 = *(const float4*)&fa[c][s0 + 4];
    a0[0] = fmaf(w.x, f0.x, a0[0]); a0[1] = fmaf(w.x, f0.y, a0[1]);
    a0[2] = fmaf(w.x, f0.z, a0[2]); a0[3] = fmaf(w.x, f0.w, a0[3]);
    a0[4] = fmaf(w.x, f1.x, a0[4]); a0[5] = fmaf(w.x, f1.y, a0[5]);
    a0[6] = fmaf(w.x, f1.z, a0[6]); a0[7] = fmaf(w.x, f1.w, a0[7]);
    a1[0] = fmaf(w.y, f0.x, a1[0]); a1[1] = fmaf(w.y, f0.y, a1[1]);
    a1[2] = fmaf(w.y, f0.z, a1[2]); a1[3] = fmaf(w.y, f0.w, a1[3]);
    a1[4] = fmaf(w.y, f1.x, a1[4]); a1[5] = fmaf(w.y, f1.y, a1[5]);
    a1[6] = fmaf(w.y, f1.z, a1[6]); a1[7] = fmaf(w.y, f1.w, a1[7]);
  }
  {
    float c0 = bm[o2], c1 = bm[o2 + 1];
    float t0 = msc[o2], t1 = msc[o2 + 1];
    float q0 = mbi[o2], q1 = mbi[o2 + 1];
#pragma unroll
    for (int j = 0; j < 8; ++j) {
      fb[o2][s0 + j]     = fmaxf(fmaf(a0[j] + c0, t0, q0), 0.f);
      fb[o2 + 1][s0 + j] = fmaxf(fmaf(a1[j] + c1, t1, q1), 0.f);
    }
  }
  __syncthreads();
#pragma unroll
  for (int j = 0; j < 8; ++j) { a0[j] = 0.f; a1[j] = 0.f; }
  for (int c = 0; c < 128; ++c) {
    float2 w = *(const float2*)&WmT[16384 + c * 128 + o2];
    float4 f0 = *(const float4*)&fb[c][s0];
    float4 f1 = *(const float4*)&fb[c][s0 + 4];
    a0[0] = fmaf(w.x, f0.x, a0[0]); a0[1] = fmaf(w.x, f0.y, a0[1]);
    a0[2] = fmaf(w.x, f0.z, a0[2]); a0[3] = fmaf(w.x, f0.w, a0[3]);
    a0[4] = fmaf(w.x, f1.x, a0[4]); a0[5] = fmaf(w.x, f1.y, a0[5]);
    a0[6] = fmaf(w.x, f1.z, a0[6]); a0[7] = fmaf(w.x, f1.w, a0[7]);
    a1[0] = fmaf(w.y, f0.x, a1[0]); a1[1] = fmaf(w.y, f0.y, a1[1]);
    a1[2] = fmaf(w.y, f0.z, a1[2]); a1[3] = fmaf(w.y, f0.w, a1[3]);
    a1[4] = fmaf(w.y, f1.x, a1[4]); a1[5] = fmaf(w.y, f1.y, a1[5]);
    a1[6] = fmaf(w.y, f1.z, a1[6]); a1[7] = fmaf(w.y, f1.w, a1[7]);
  }
  {
    float c0 = bm[128 + o2], c1 = bm[128 + o2 + 1];
    float t0 = msc[128 + o2], t1 = msc[128 + o2 + 1];
    float q0 = mbi[128 + o2], q1 = mbi[128 + o2 + 1];
    float4 v0a, v0b, v1a, v1b;
    v0a.x = fmaxf(fmaf(a0[0] + c0, t0, q0), 0.f);
    v0a.y = fmaxf(fmaf(a0[1] + c0, t0, q0), 0.f);
    v0a.z = fmaxf(fmaf(a0[2] + c0, t0, q0), 0.f);
    v0a.w = fmaxf(fmaf(a0[3] + c0, t0, q0), 0.f);
    v0b.x = fmaxf(fmaf(a0[4] + c0, t0, q0), 0.f);
    v0b.y = fmaxf(fmaf(a0[5] + c0, t0, q0), 0.f);
    v0b.z = fmaxf(fmaf(a0[6] + c0, t0, q0), 0.f);
    v0b.w = fmaxf(fmaf(a0[7] + c0, t0, q0), 0.f);
    v1a.x = fmaxf(fmaf(a1[0] + c1, t1, q1), 0.f);
    v1a.y = fmaxf(fmaf(a1[1] + c1, t1, q1), 0.f);
    v1a.z = fmaxf(fmaf(a1[2] + c1, t1, q1), 0.f);
    v1a.w = fmaxf(fmaf(a1[3] + c1, t1, q1), 0.f);
    v1b.x = fmaxf(fmaf(a1[4] + c1, t1, q1), 0.f);
    v1b.y = fmaxf(fmaf(a1[5] + c1, t1, q1), 0.f);
    v1b.z = fmaxf(fmaf(a1[6] + c1, t1, q1), 0.f);
    v1b.w = fmaxf(fmaf(a1[7] + c1, t1, q1), 0.f);
    float* p0 = &out_feat[((size_t)b * 128 + o2) * 128 + sbase + s0];
    float* p1 = &out_feat[((size_t)b * 128 + o2 + 1) * 128 + sbase + s0];
    *(float4*)p0 = v0a;
    *(float4*)(p0 + 4) = v0b;
    *(float4*)p1 = v1a;
    *(float4*)(p1 + 4) = v1b;
  }
}

extern "C" void kernel_launch(void* const* d_in, const int* in_sizes, int n_in,
                              void* d_out, int out_size, void* d_ws, size_t ws_size,
                              hipStream_t stream) {
  const float* vote_xyz  = (const float*)d_in[0];
  const float* vote_feat = (const float*)d_in[1];
  const float* W1   = (const float*)d_in[2];
  const float* W2   = (const float*)d_in[3];
  const float* W3   = (const float*)d_in[4];
  const float* sasc = (const float*)d_in[5];
  const float* sabi = (const float*)d_in[6];
  const float* Wm   = (const float*)d_in[7];
  const float* bm   = (const float*)d_in[8];
  const float* msc  = (const float*)d_in[9];
  const float* mbi  = (const float*)d_in[10];

  float* out = (float*)d_out;
  float* out_xyz  = out;                    // B*NP*3   = 6144
  float* out_feat = out + 6144;             // B*128*NP = 262144
  float* out_indf = out + 6144 + 262144;    // B*NP     = 2048

  char* ws = (char*)d_ws;
  int*   fps_ws  = (int*)(ws + 0);          //   8 KB
  float* centers = (float*)(ws + 8192);     //  24 KB
  int*   bidx    = (int*)(ws + 32768);      // 128 KB
  float* W1T     = (float*)(ws + 163840);   // 132608 B
  float* W2T     = (float*)(ws + 296448);   //  64 KB
  float* W3T     = (float*)(ws + 361984);   //  64 KB
  float* WmT     = (float*)(ws + 427520);   // 128 KB
  float* feat0   = (float*)(ws + 558592);   //   1 MB

  hipLaunchKernelGGL(transpose_kernel, dim3(130), dim3(256), 0, stream,
                     W1, W2, W3, Wm, W1T, W2T, W3T, WmT);
  hipLaunchKernelGGL(fps_kernel, dim3(NB), dim3(FTH), 0, stream,
                     vote_xyz, fps_ws, centers, out_xyz, out_indf);
  hipLaunchKernelGGL(ballq_kernel, dim3(NB * NPP), dim3(64), 0, stream,
                     vote_xyz, centers, bidx);
  hipLaunchKernelGGL(mlp_kernel, dim3(NB * NPP), dim3(256), 0, stream,
                     vote_xyz, vote_feat, centers, bidx, W1T, W2T, W3T,
                     sasc, sabi, feat0);
  hipLaunchKernelGGL(head_kernel, dim3(NB * 4), dim3(256), 0, stream,
                     feat0, WmT, bm, msc, mbi, out_feat);
}

// Round 6
// 411.201 us; speedup vs baseline: 1.0472x; 1.0472x over previous
//
#include <hip/hip_runtime.h>
#include <hip/hip_bf16.h>

#define NB  16
#define NN  16384
#define NC  256
#define NPP 128
#define NSS 16

#define FTH 1024  // fps threads per block (16 waves, 4 waves/SIMD)
#define FPT 16    // fps points per thread -> 64 array VGPRs, fits <128 target

// ---------------- weight transpose (one-shot, tiny) ----------------
__global__ __launch_bounds__(256) void transpose_kernel(
    const float* __restrict__ W1, const float* __restrict__ W2,
    const float* __restrict__ W3, const float* __restrict__ Wm,
    float* __restrict__ W1T, float* __restrict__ W2T,
    float* __restrict__ W3T, float* __restrict__ WmT) {
  int i = blockIdx.x * 256 + threadIdx.x;
  if (i < 128 * 259) { int o = i / 259, c = i - o * 259; W1T[c * 128 + o] = W1[i]; }
  if (i < 128 * 128) {
    int o = i >> 7, c = i & 127;
    W2T[c * 128 + o] = W2[i];
    W3T[c * 128 + o] = W3[i];
    WmT[c * 128 + o] = Wm[i];
    WmT[16384 + c * 128 + o] = Wm[16384 + i];
  }
}

// ---------------- FPS: one block per batch ----------------
// Exact numpy semantics: d = ((dx*dx + dy*dy) + dz*dz), per-op rounding,
// argmax tie-break = lowest index via packed u64 max:
//   pack = (f32bits(val) << 32) | (0xFFFFFFFF - idx)
// Register-residency design: 16 pts/thread -> X/Y/Z/MD = 64 VGPRs + temps
// ~90 < the compiler's 4-waves/SIMD 128-reg target, so NO load sinking /
// spilling (rounds 2-5 all hit remat at 128+ live floats -> 1.8-1.9 us/iter).
// Wave reduce: 4x DPP row_ror (VALU-only) + ds_swizzle xor16 + shfl_xor 32
// = 4 LDS ops/thread (vs 12 bpermute butterfly). One barrier per iteration.
__global__ __launch_bounds__(FTH, 4) void fps_kernel(
    const float* __restrict__ xyz,
    float* __restrict__ centers, float* __restrict__ out_xyz,
    float* __restrict__ out_indf) {
  int b = blockIdx.x;
  const float* px = xyz + (size_t)b * (NN * 3);
  int t = threadIdx.x;
  float X[FPT], Y[FPT], Z[FPT], MD[FPT];
#pragma unroll
  for (int j = 0; j < FPT; ++j) {
    int n = t + j * FTH;
    float x = px[n * 3 + 0];
    float y = px[n * 3 + 1];
    float z = px[n * 3 + 2];
    asm volatile("" : "+v"(x), "+v"(y), "+v"(z));  // forbid re-loading
    X[j] = x; Y[j] = y; Z[j] = z;
    MD[j] = 1e10f;
  }
  __shared__ unsigned long long cand[2][16];
  float cx = px[0], cy = px[1], cz = px[2];
  if (t == 0) {
    out_indf[b * NPP] = 0.0f;
    centers[(b * NPP) * 3 + 0] = cx;
    centers[(b * NPP) * 3 + 1] = cy;
    centers[(b * NPP) * 3 + 2] = cz;
    out_xyz[(b * NPP) * 3 + 0] = cx;
    out_xyz[(b * NPP) * 3 + 1] = cy;
    out_xyz[(b * NPP) * 3 + 2] = cz;
  }
  for (int it = 1; it < NPP; ++it) {
    float bv = -1.0f;
    int bi = 0;
#pragma unroll
    for (int j = 0; j < FPT; ++j) {
      float dx = __fsub_rn(X[j], cx);
      float dy = __fsub_rn(Y[j], cy);
      float dz = __fsub_rn(Z[j], cz);
      float d  = __fadd_rn(__fadd_rn(__fmul_rn(dx, dx), __fmul_rn(dy, dy)),
                           __fmul_rn(dz, dz));
      float m = fminf(MD[j], d);
      MD[j] = m;
      if (m > bv) { bv = m; bi = t + j * FTH; }  // first occurrence kept
    }
    unsigned long long pk =
        (((unsigned long long)__float_as_uint(bv)) << 32) |
        (unsigned long long)(0xFFFFFFFFu - (unsigned)bi);
    // ---- wave64 max-reduce of pk ----
    // rows of 16 via DPP row_ror (VALU only):
#define STEP_ROR(N)                                                         \
    {                                                                       \
      unsigned lo = (unsigned)pk, hi = (unsigned)(pk >> 32);                \
      lo = (unsigned)__builtin_amdgcn_mov_dpp((int)lo, 0x120 | N, 0xF, 0xF, true); \
      hi = (unsigned)__builtin_amdgcn_mov_dpp((int)hi, 0x120 | N, 0xF, 0xF, true); \
      unsigned long long o = ((unsigned long long)hi << 32) | lo;           \
      if (o > pk) pk = o;                                                   \
    }
    STEP_ROR(1) STEP_ROR(2) STEP_ROR(4) STEP_ROR(8)
#undef STEP_ROR
    {  // lane ^ 16 within 32-lane halves (ds_swizzle BitMode 0x401F)
      unsigned lo = (unsigned)pk, hi = (unsigned)(pk >> 32);
      lo = (unsigned)__builtin_amdgcn_ds_swizzle((int)lo, 0x401F);
      hi = (unsigned)__builtin_amdgcn_ds_swizzle((int)hi, 0x401F);
      unsigned long long o = ((unsigned long long)hi << 32) | lo;
      if (o > pk) pk = o;
    }
    {  // lane ^ 32
      unsigned long long o = __shfl_xor(pk, 32, 64);
      if (o > pk) pk = o;
    }
    if ((t & 63) == 0) cand[it & 1][t >> 6] = pk;
    __syncthreads();
    const unsigned long long* cp = cand[it & 1];
    unsigned long long mx = cp[0];
#pragma unroll
    for (int w = 1; w < 16; ++w) {
      unsigned long long v = cp[w];
      if (v > mx) mx = v;
    }
    int win = (int)(0xFFFFFFFFu - (unsigned)(mx & 0xFFFFFFFFull));
    win = __builtin_amdgcn_readfirstlane(win);
    cx = px[win * 3 + 0];
    cy = px[win * 3 + 1];
    cz = px[win * 3 + 2];
    if (t == 0) {
      out_indf[b * NPP + it] = (float)win;
      centers[(b * NPP + it) * 3 + 0] = cx;
      centers[(b * NPP + it) * 3 + 1] = cy;
      centers[(b * NPP + it) * 3 + 2] = cz;
      out_xyz[(b * NPP + it) * 3 + 0] = cx;
      out_xyz[(b * NPP + it) * 3 + 1] = cy;
      out_xyz[(b * NPP + it) * 3 + 2] = cz;
    }
  }
}

// ---------------- ball query: one wave per (b, center) ----------------
__global__ __launch_bounds__(64) void ballq_kernel(
    const float* __restrict__ xyz, const float* __restrict__ centers,
    int* __restrict__ bidx) {
  int bs = blockIdx.x;  // b*128 + s
  int b = bs >> 7;
  int lane = threadIdx.x;
  const float* px = xyz + (size_t)b * (NN * 3);
  float cx = centers[bs * 3 + 0];
  float cy = centers[bs * 3 + 1];
  float cz = centers[bs * 3 + 2];
  __shared__ int coll[NSS];
  const float rr = 0.09f;  // f32(0.09): identical membership to f64 compare
  int have = 0;
  for (int c0 = 0; c0 < NN; c0 += 64) {
    int n = c0 + lane;
    float dx = __fsub_rn(px[n * 3 + 0], cx);
    float dy = __fsub_rn(px[n * 3 + 1], cy);
    float dz = __fsub_rn(px[n * 3 + 2], cz);
    float d2 = __fadd_rn(__fadd_rn(__fmul_rn(dx, dx), __fmul_rn(dy, dy)),
                         __fmul_rn(dz, dz));
    bool in = d2 < rr;
    unsigned long long m = __ballot(in);
    if (in) {
      int pos = have + __popcll(m & ((1ull << lane) - 1ull));
      if (pos < NSS) coll[pos] = n;
    }
    have += __popcll(m);
    if (have >= NSS) break;
  }
  __syncthreads();
  int first = coll[0];
  if (lane < NSS) bidx[bs * NSS + lane] = (lane < have) ? coll[lane] : first;
}

// ---------------- grouped MLP (3 layers + maxpool over NS) ----------------
__device__ __forceinline__ void layer_f(const float (*in)[20], int cin,
                                        const float* __restrict__ WT,
                                        const float* __restrict__ sc,
                                        const float* __restrict__ bi,
                                        int o2, int k0, float4& r0, float4& r1) {
  float a0[4] = {0.f, 0.f, 0.f, 0.f};
  float a1[4] = {0.f, 0.f, 0.f, 0.f};
  for (int c = 0; c < cin; ++c) {
    float2 w = *(const float2*)(WT + c * 128 + o2);
    float4 gv = *(const float4*)(&in[c][k0]);
    a0[0] = fmaf(w.x, gv.x, a0[0]);
    a0[1] = fmaf(w.x, gv.y, a0[1]);
    a0[2] = fmaf(w.x, gv.z, a0[2]);
    a0[3] = fmaf(w.x, gv.w, a0[3]);
    a1[0] = fmaf(w.y, gv.x, a1[0]);
    a1[1] = fmaf(w.y, gv.y, a1[1]);
    a1[2] = fmaf(w.y, gv.z, a1[2]);
    a1[3] = fmaf(w.y, gv.w, a1[3]);
  }
  float s0 = sc[o2], s1 = sc[o2 + 1], b0 = bi[o2], b1 = bi[o2 + 1];
  r0.x = fmaxf(fmaf(a0[0], s0, b0), 0.f);
  r0.y = fmaxf(fmaf(a0[1], s0, b0), 0.f);
  r0.z = fmaxf(fmaf(a0[2], s0, b0), 0.f);
  r0.w = fmaxf(fmaf(a0[3], s0, b0), 0.f);
  r1.x = fmaxf(fmaf(a1[0], s1, b1), 0.f);
  r1.y = fmaxf(fmaf(a1[1], s1, b1), 0.f);
  r1.z = fmaxf(fmaf(a1[2], s1, b1), 0.f);
  r1.w = fmaxf(fmaf(a1[3], s1, b1), 0.f);
}

__global__ __launch_bounds__(256) void mlp_kernel(
    const float* __restrict__ xyz, const float* __restrict__ feats,
    const float* __restrict__ centers, const int* __restrict__ bidx,
    const float* __restrict__ W1T, const float* __restrict__ W2T,
    const float* __restrict__ W3T, const float* __restrict__ sa_sc,
    const float* __restrict__ sa_bi, float* __restrict__ feat0) {
  int bs = blockIdx.x;
  int b = bs >> 7;
  int s = bs & 127;
  int tid = threadIdx.x;
  __shared__ float g[259][20];
  __shared__ float h1[128][20];
  __shared__ float h2[128][20];
  __shared__ int kidx[NSS];
  __shared__ float ctr[3];
  if (tid < NSS) kidx[tid] = bidx[bs * NSS + tid];
  if (tid < 3) ctr[tid] = centers[bs * 3 + tid];
  __syncthreads();
  const float* px = xyz + (size_t)b * (NN * 3);
  if (tid < NSS) {
    int n = kidx[tid];
    g[0][tid] = __fdiv_rn(__fsub_rn(px[n * 3 + 0], ctr[0]), 0.3f);
    g[1][tid] = __fdiv_rn(__fsub_rn(px[n * 3 + 1], ctr[1]), 0.3f);
    g[2][tid] = __fdiv_rn(__fsub_rn(px[n * 3 + 2], ctr[2]), 0.3f);
  }
  {
    const float* row = feats + ((size_t)b * NC + tid) * NN;
#pragma unroll
    for (int k = 0; k < NSS; ++k) g[3 + tid][k] = row[kidx[k]];
  }
  __syncthreads();
  int o2 = (tid & 63) * 2;
  int k0 = (tid >> 6) * 4;
  float4 r0, r1;
  layer_f(g, 259, W1T, sa_sc, sa_bi, o2, k0, r0, r1);
  *(float4*)&h1[o2][k0] = r0;
  *(float4*)&h1[o2 + 1][k0] = r1;
  __syncthreads();
  layer_f(h1, 128, W2T, sa_sc + 128, sa_bi + 128, o2, k0, r0, r1);
  *(float4*)&h2[o2][k0] = r0;
  *(float4*)&h2[o2 + 1][k0] = r1;
  __syncthreads();
  layer_f(h2, 128, W3T, sa_sc + 256, sa_bi + 256, o2, k0, r0, r1);
  float m0 = fmaxf(fmaxf(r0.x, r0.y), fmaxf(r0.z, r0.w));
  float m1 = fmaxf(fmaxf(r1.x, r1.y), fmaxf(r1.z, r1.w));
  int w = tid >> 6;
  h1[o2][w] = m0;
  h1[o2 + 1][w] = m1;
  __syncthreads();
  if (tid < 128) {
    float m = fmaxf(fmaxf(h1[tid][0], h1[tid][1]), fmaxf(h1[tid][2], h1[tid][3]));
    feat0[((size_t)b * 128 + tid) * 128 + s] = m;
  }
}

// ---------------- FC heads: (x@Wm + bm)*scale + bias, relu, x2 ----------------
__global__ __launch_bounds__(256) void head_kernel(
    const float* __restrict__ feat0, const float* __restrict__ WmT,
    const float* __restrict__ bm, const float* __restrict__ msc,
    const float* __restrict__ mbi, float* __restrict__ out_feat) {
  int blk = blockIdx.x;
  int b = blk >> 2;
  int sbase = (blk & 3) * 32;
  int tid = threadIdx.x;
  __shared__ float fa[128][36];
  __shared__ float fb[128][36];
  {
    int sj = tid & 31, c0 = tid >> 5;
    for (int c = c0; c < 128; c += 8)
      fa[c][sj] = feat0[((size_t)b * 128 + c) * 128 + sbase + sj];
  }
  __syncthreads();
  int o2 = (tid & 63) * 2, s0 = (tid >> 6) * 8;
  float a0[8], a1[8];
#pragma unroll
  for (int j = 0; j < 8; ++j) { a0[j] = 0.f; a1[j] = 0.f; }
  for (int c = 0; c < 128; ++c) {
    float2 w = *(const float2*)&WmT[c * 128 + o2];
    float4 f0 = *(const float4*)&fa[c][s0];
    float4 f1 = *(const float4*)&fa[c][s0 + 4];
    a0[0] = fmaf(w.x, f0.x, a0[0]); a0[1] = fmaf(w.x, f0.y, a0[1]);
    a0[2] = fmaf(w.x, f0.z, a0[2]); a0[3] = fmaf(w.x, f0.w, a0[3]);
    a0[4] = fmaf(w.x, f1.x, a0[4]); a0[5] = fmaf(w.x, f1.y, a0[5]);
    a0[6] = fmaf(w.x, f1.z, a0[6]); a0[7] = fmaf(w.x, f1.w, a0[7]);
    a1[0] = fmaf(w.y, f0.x, a1[0]); a1[1] = fmaf(w.y, f0.y, a1[1]);
    a1[2] = fmaf(w.y, f0.z, a1[2]); a1[3] = fmaf(w.y, f0.w, a1[3]);
    a1[4] = fmaf(w.y, f1.x, a1[4]); a1[5] = fmaf(w.y, f1.y, a1[5]);
    a1[6] = fmaf(w.y, f1.z, a1[6]); a1[7] = fmaf(w.y, f1.w, a1[7]);
  }
  {
    float c0 = bm[o2], c1 = bm[o2 + 1];
    float t0 = msc[o2], t1 = msc[o2 + 1];
    float q0 = mbi[o2], q1 = mbi[o2 + 1];
#pragma unroll
    for (int j = 0; j < 8; ++j) {
      fb[o2][s0 + j]     = fmaxf(fmaf(a0[j] + c0, t0, q0), 0.f);
      fb[o2 + 1][s0 + j] = fmaxf(fmaf(a1[j] + c1, t1, q1), 0.f);
    }
  }
  __syncthreads();
#pragma unroll
  for (int j = 0; j < 8; ++j) { a0[j] = 0.f; a1[j] = 0.f; }
  for (int c = 0; c < 128; ++c) {
    float2 w = *(const float2*)&WmT[16384 + c * 128 + o2];
    float4 f0 = *(const float4*)&fb[c][s0];
    float4 f1 = *(const float4*)&fb[c][s0 + 4];
    a0[0] = fmaf(w.x, f0.x, a0[0]); a0[1] = fmaf(w.x, f0.y, a0[1]);
    a0[2] = fmaf(w.x, f0.z, a0[2]); a0[3] = fmaf(w.x, f0.w, a0[3]);
    a0[4] = fmaf(w.x, f1.x, a0[4]); a0[5] = fmaf(w.x, f1.y, a0[5]);
    a0[6] = fmaf(w.x, f1.z, a0[6]); a0[7] = fmaf(w.x, f1.w, a0[7]);
    a1[0] = fmaf(w.y, f0.x, a1[0]); a1[1] = fmaf(w.y, f0.y, a1[1]);
    a1[2] = fmaf(w.y, f0.z, a1[2]); a1[3] = fmaf(w.y, f0.w, a1[3]);
    a1[4] = fmaf(w.y, f1.x, a1[4]); a1[5] = fmaf(w.y, f1.y, a1[5]);
    a1[6] = fmaf(w.y, f1.z, a1[6]); a1[7] = fmaf(w.y, f1.w, a1[7]);
  }
  {
    float c0 = bm[128 + o2], c1 = bm[128 + o2 + 1];
    float t0 = msc[128 + o2], t1 = msc[128 + o2 + 1];
    float q0 = mbi[128 + o2], q1 = mbi[128 + o2 + 1];
    float4 v0a, v0b, v1a, v1b;
    v0a.x = fmaxf(fmaf(a0[0] + c0, t0, q0), 0.f);
    v0a.y = fmaxf(fmaf(a0[1] + c0, t0, q0), 0.f);
    v0a.z = fmaxf(fmaf(a0[2] + c0, t0, q0), 0.f);
    v0a.w = fmaxf(fmaf(a0[3] + c0, t0, q0), 0.f);
    v0b.x = fmaxf(fmaf(a0[4] + c0, t0, q0), 0.f);
    v0b.y = fmaxf(fmaf(a0[5] + c0, t0, q0), 0.f);
    v0b.z = fmaxf(fmaf(a0[6] + c0, t0, q0), 0.f);
    v0b.w = fmaxf(fmaf(a0[7] + c0, t0, q0), 0.f);
    v1a.x = fmaxf(fmaf(a1[0] + c1, t1, q1), 0.f);
    v1a.y = fmaxf(fmaf(a1[1] + c1, t1, q1), 0.f);
    v1a.z = fmaxf(fmaf(a1[2] + c1, t1, q1), 0.f);
    v1a.w = fmaxf(fmaf(a1[3] + c1, t1, q1), 0.f);
    v1b.x = fmaxf(fmaf(a1[4] + c1, t1, q1), 0.f);
    v1b.y = fmaxf(fmaf(a1[5] + c1, t1, q1), 0.f);
    v1b.z = fmaxf(fmaf(a1[6] + c1, t1, q1), 0.f);
    v1b.w = fmaxf(fmaf(a1[7] + c1, t1, q1), 0.f);
    float* p0 = &out_feat[((size_t)b * 128 + o2) * 128 + sbase + s0];
    float* p1 = &out_feat[((size_t)b * 128 + o2 + 1) * 128 + sbase + s0];
    *(float4*)p0 = v0a;
    *(float4*)(p0 + 4) = v0b;
    *(float4*)p1 = v1a;
    *(float4*)(p1 + 4) = v1b;
  }
}

extern "C" void kernel_launch(void* const* d_in, const int* in_sizes, int n_in,
                              void* d_out, int out_size, void* d_ws, size_t ws_size,
                              hipStream_t stream) {
  const float* vote_xyz  = (const float*)d_in[0];
  const float* vote_feat = (const float*)d_in[1];
  const float* W1   = (const float*)d_in[2];
  const float* W2   = (const float*)d_in[3];
  const float* W3   = (const float*)d_in[4];
  const float* sasc = (const float*)d_in[5];
  const float* sabi = (const float*)d_in[6];
  const float* Wm   = (const float*)d_in[7];
  const float* bm   = (const float*)d_in[8];
  const float* msc  = (const float*)d_in[9];
  const float* mbi  = (const float*)d_in[10];

  float* out = (float*)d_out;
  float* out_xyz  = out;                    // B*NP*3   = 6144
  float* out_feat = out + 6144;             // B*128*NP = 262144
  float* out_indf = out + 6144 + 262144;    // B*NP     = 2048

  char* ws = (char*)d_ws;
  float* centers = (float*)(ws + 8192);     //  24 KB
  int*   bidx    = (int*)(ws + 32768);      // 128 KB
  float* W1T     = (float*)(ws + 163840);   // 132608 B
  float* W2T     = (float*)(ws + 296448);   //  64 KB
  float* W3T     = (float*)(ws + 361984);   //  64 KB
  float* WmT     = (float*)(ws + 427520);   // 128 KB
  float* feat0   = (float*)(ws + 558592);   //   1 MB

  hipLaunchKernelGGL(transpose_kernel, dim3(130), dim3(256), 0, stream,
                     W1, W2, W3, Wm, W1T, W2T, W3T, WmT);
  hipLaunchKernelGGL(fps_kernel, dim3(NB), dim3(FTH), 0, stream,
                     vote_xyz, centers, out_xyz, out_indf);
  hipLaunchKernelGGL(ballq_kernel, dim3(NB * NPP), dim3(64), 0, stream,
                     vote_xyz, centers, bidx);
  hipLaunchKernelGGL(mlp_kernel, dim3(NB * NPP), dim3(256), 0, stream,
                     vote_xyz, vote_feat, centers, bidx, W1T, W2T, W3T,
                     sasc, sabi, feat0);
  hipLaunchKernelGGL(head_kernel, dim3(NB * 4), dim3(256), 0, stream,
                     feat0, WmT, bm, msc, mbi, out_feat);
}

// Round 7
// 410.443 us; speedup vs baseline: 1.0491x; 1.0018x over previous
//
#include <hip/hip_runtime.h>
#include <hip/hip_bf16.h>

#define NB  16
#define NN  16384
#define NC  256
#define NPP 128
#define NSS 16

#define FTH 1024  // fps threads per block (16 waves = 4 waves/SIMD exactly)
#define FPT 16    // fps points per thread -> X/Y/Z/MD = 64 array VGPRs

// ---------------- weight transpose (one-shot, tiny) ----------------
__global__ __launch_bounds__(256) void transpose_kernel(
    const float* __restrict__ W1, const float* __restrict__ W2,
    const float* __restrict__ W3, const float* __restrict__ Wm,
    float* __restrict__ W1T, float* __restrict__ W2T,
    float* __restrict__ W3T, float* __restrict__ WmT) {
  int i = blockIdx.x * 256 + threadIdx.x;
  if (i < 128 * 259) { int o = i / 259, c = i - o * 259; W1T[c * 128 + o] = W1[i]; }
  if (i < 128 * 128) {
    int o = i >> 7, c = i & 127;
    W2T[c * 128 + o] = W2[i];
    W3T[c * 128 + o] = W3[i];
    WmT[c * 128 + o] = Wm[i];
    WmT[16384 + c * 128 + o] = Wm[16384 + i];
  }
}

// ---------------- FPS: one block per batch ----------------
// Exact numpy semantics: d = ((dx*dx + dy*dy) + dz*dz), per-op rounding,
// argmax tie-break = lowest index via packed u64 max:
//   pack = (f32bits(val) << 32) | (0xFFFFFFFF - idx)
// REGISTER RESIDENCY: rounds 2-6 all plateaued at ~1.8us/iter because the
// allocator budgeted for 8+ waves/EU (VGPR_Count 48-88) and spilled the
// 64-float per-thread state to scratch (~256KB/CU/iter round-trip).
// amdgpu_waves_per_eu(4,4) pins the budget to 128 VGPRs (4 waves/SIMD),
// which fits 64 array regs + temps -> no spill, j-loop is pure VALU.
__global__ __attribute__((amdgpu_flat_work_group_size(1024, 1024),
                          amdgpu_waves_per_eu(4, 4)))
void fps_kernel(
    const float* __restrict__ xyz,
    float* __restrict__ centers, float* __restrict__ out_xyz,
    float* __restrict__ out_indf) {
  int b = blockIdx.x;
  const float* px = xyz + (size_t)b * (NN * 3);
  int t = threadIdx.x;
  float X[FPT], Y[FPT], Z[FPT], MD[FPT];
#pragma unroll
  for (int j = 0; j < FPT; ++j) {
    int n = t + j * FTH;
    float x = px[n * 3 + 0];
    float y = px[n * 3 + 1];
    float z = px[n * 3 + 2];
    asm volatile("" : "+v"(x), "+v"(y), "+v"(z));  // forbid re-loading
    X[j] = x; Y[j] = y; Z[j] = z;
    MD[j] = 1e10f;
  }
  __shared__ unsigned long long cand[2][16];
  float cx = px[0], cy = px[1], cz = px[2];
  if (t == 0) {
    out_indf[b * NPP] = 0.0f;
    centers[(b * NPP) * 3 + 0] = cx;
    centers[(b * NPP) * 3 + 1] = cy;
    centers[(b * NPP) * 3 + 2] = cz;
    out_xyz[(b * NPP) * 3 + 0] = cx;
    out_xyz[(b * NPP) * 3 + 1] = cy;
    out_xyz[(b * NPP) * 3 + 2] = cz;
  }
  for (int it = 1; it < NPP; ++it) {
    float bv = -1.0f;
    int bi = 0;
#pragma unroll
    for (int j = 0; j < FPT; ++j) {
      float dx = __fsub_rn(X[j], cx);
      float dy = __fsub_rn(Y[j], cy);
      float dz = __fsub_rn(Z[j], cz);
      float d  = __fadd_rn(__fadd_rn(__fmul_rn(dx, dx), __fmul_rn(dy, dy)),
                           __fmul_rn(dz, dz));
      float m = fminf(MD[j], d);
      MD[j] = m;
      if (m > bv) { bv = m; bi = t + j * FTH; }  // first occurrence kept
    }
    unsigned long long pk =
        (((unsigned long long)__float_as_uint(bv)) << 32) |
        (unsigned long long)(0xFFFFFFFFu - (unsigned)bi);
    // ---- wave64 max-reduce of pk ----
    // rows of 16 via DPP row_ror (VALU only):
#define STEP_ROR(N)                                                         \
    {                                                                       \
      unsigned lo = (unsigned)pk, hi = (unsigned)(pk >> 32);                \
      lo = (unsigned)__builtin_amdgcn_mov_dpp((int)lo, 0x120 | N, 0xF, 0xF, true); \
      hi = (unsigned)__builtin_amdgcn_mov_dpp((int)hi, 0x120 | N, 0xF, 0xF, true); \
      unsigned long long o = ((unsigned long long)hi << 32) | lo;           \
      if (o > pk) pk = o;                                                   \
    }
    STEP_ROR(1) STEP_ROR(2) STEP_ROR(4) STEP_ROR(8)
#undef STEP_ROR
    {  // lane ^ 16 within 32-lane halves (ds_swizzle BitMode 0x401F)
      unsigned lo = (unsigned)pk, hi = (unsigned)(pk >> 32);
      lo = (unsigned)__builtin_amdgcn_ds_swizzle((int)lo, 0x401F);
      hi = (unsigned)__builtin_amdgcn_ds_swizzle((int)hi, 0x401F);
      unsigned long long o = ((unsigned long long)hi << 32) | lo;
      if (o > pk) pk = o;
    }
    {  // lane ^ 32
      unsigned long long o = __shfl_xor(pk, 32, 64);
      if (o > pk) pk = o;
    }
    if ((t & 63) == 0) cand[it & 1][t >> 6] = pk;
    __syncthreads();
    const unsigned long long* cp = cand[it & 1];
    unsigned long long mx = cp[0];
#pragma unroll
    for (int w = 1; w < 16; ++w) {
      unsigned long long v = cp[w];
      if (v > mx) mx = v;
    }
    int win = (int)(0xFFFFFFFFu - (unsigned)(mx & 0xFFFFFFFFull));
    win = __builtin_amdgcn_readfirstlane(win);
    cx = px[win * 3 + 0];
    cy = px[win * 3 + 1];
    cz = px[win * 3 + 2];
    if (t == 0) {
      out_indf[b * NPP + it] = (float)win;
      centers[(b * NPP + it) * 3 + 0] = cx;
      centers[(b * NPP + it) * 3 + 1] = cy;
      centers[(b * NPP + it) * 3 + 2] = cz;
      out_xyz[(b * NPP + it) * 3 + 0] = cx;
      out_xyz[(b * NPP + it) * 3 + 1] = cy;
      out_xyz[(b * NPP + it) * 3 + 2] = cz;
    }
  }
}

// ---------------- ball query: one wave per (b, center) ----------------
__global__ __launch_bounds__(64) void ballq_kernel(
    const float* __restrict__ xyz, const float* __restrict__ centers,
    int* __restrict__ bidx) {
  int bs = blockIdx.x;  // b*128 + s
  int b = bs >> 7;
  int lane = threadIdx.x;
  const float* px = xyz + (size_t)b * (NN * 3);
  float cx = centers[bs * 3 + 0];
  float cy = centers[bs * 3 + 1];
  float cz = centers[bs * 3 + 2];
  __shared__ int coll[NSS];
  const float rr = 0.09f;  // f32(0.09): identical membership to f64 compare
  int have = 0;
  for (int c0 = 0; c0 < NN; c0 += 64) {
    int n = c0 + lane;
    float dx = __fsub_rn(px[n * 3 + 0], cx);
    float dy = __fsub_rn(px[n * 3 + 1], cy);
    float dz = __fsub_rn(px[n * 3 + 2], cz);
    float d2 = __fadd_rn(__fadd_rn(__fmul_rn(dx, dx), __fmul_rn(dy, dy)),
                         __fmul_rn(dz, dz));
    bool in = d2 < rr;
    unsigned long long m = __ballot(in);
    if (in) {
      int pos = have + __popcll(m & ((1ull << lane) - 1ull));
      if (pos < NSS) coll[pos] = n;
    }
    have += __popcll(m);
    if (have >= NSS) break;
  }
  __syncthreads();
  int first = coll[0];
  if (lane < NSS) bidx[bs * NSS + lane] = (lane < have) ? coll[lane] : first;
}

// ---------------- grouped MLP (3 layers + maxpool over NS) ----------------
__device__ __forceinline__ void layer_f(const float (*in)[20], int cin,
                                        const float* __restrict__ WT,
                                        const float* __restrict__ sc,
                                        const float* __restrict__ bi,
                                        int o2, int k0, float4& r0, float4& r1) {
  float a0[4] = {0.f, 0.f, 0.f, 0.f};
  float a1[4] = {0.f, 0.f, 0.f, 0.f};
  for (int c = 0; c < cin; ++c) {
    float2 w = *(const float2*)(WT + c * 128 + o2);
    float4 gv = *(const float4*)(&in[c][k0]);
    a0[0] = fmaf(w.x, gv.x, a0[0]);
    a0[1] = fmaf(w.x, gv.y, a0[1]);
    a0[2] = fmaf(w.x, gv.z, a0[2]);
    a0[3] = fmaf(w.x, gv.w, a0[3]);
    a1[0] = fmaf(w.y, gv.x, a1[0]);
    a1[1] = fmaf(w.y, gv.y, a1[1]);
    a1[2] = fmaf(w.y, gv.z, a1[2]);
    a1[3] = fmaf(w.y, gv.w, a1[3]);
  }
  float s0 = sc[o2], s1 = sc[o2 + 1], b0 = bi[o2], b1 = bi[o2 + 1];
  r0.x = fmaxf(fmaf(a0[0], s0, b0), 0.f);
  r0.y = fmaxf(fmaf(a0[1], s0, b0), 0.f);
  r0.z = fmaxf(fmaf(a0[2], s0, b0), 0.f);
  r0.w = fmaxf(fmaf(a0[3], s0, b0), 0.f);
  r1.x = fmaxf(fmaf(a1[0], s1, b1), 0.f);
  r1.y = fmaxf(fmaf(a1[1], s1, b1), 0.f);
  r1.z = fmaxf(fmaf(a1[2], s1, b1), 0.f);
  r1.w = fmaxf(fmaf(a1[3], s1, b1), 0.f);
}

__global__ __launch_bounds__(256) void mlp_kernel(
    const float* __restrict__ xyz, const float* __restrict__ feats,
    const float* __restrict__ centers, const int* __restrict__ bidx,
    const float* __restrict__ W1T, const float* __restrict__ W2T,
    const float* __restrict__ W3T, const float* __restrict__ sa_sc,
    const float* __restrict__ sa_bi, float* __restrict__ feat0) {
  int bs = blockIdx.x;
  int b = bs >> 7;
  int s = bs & 127;
  int tid = threadIdx.x;
  __shared__ float g[259][20];
  __shared__ float h1[128][20];
  __shared__ float h2[128][20];
  __shared__ int kidx[NSS];
  __shared__ float ctr[3];
  if (tid < NSS) kidx[tid] = bidx[bs * NSS + tid];
  if (tid < 3) ctr[tid] = centers[bs * 3 + tid];
  __syncthreads();
  const float* px = xyz + (size_t)b * (NN * 3);
  if (tid < NSS) {
    int n = kidx[tid];
    g[0][tid] = __fdiv_rn(__fsub_rn(px[n * 3 + 0], ctr[0]), 0.3f);
    g[1][tid] = __fdiv_rn(__fsub_rn(px[n * 3 + 1], ctr[1]), 0.3f);
    g[2][tid] = __fdiv_rn(__fsub_rn(px[n * 3 + 2], ctr[2]), 0.3f);
  }
  {
    const float* row = feats + ((size_t)b * NC + tid) * NN;
#pragma unroll
    for (int k = 0; k < NSS; ++k) g[3 + tid][k] = row[kidx[k]];
  }
  __syncthreads();
  int o2 = (tid & 63) * 2;
  int k0 = (tid >> 6) * 4;
  float4 r0, r1;
  layer_f(g, 259, W1T, sa_sc, sa_bi, o2, k0, r0, r1);
  *(float4*)&h1[o2][k0] = r0;
  *(float4*)&h1[o2 + 1][k0] = r1;
  __syncthreads();
  layer_f(h1, 128, W2T, sa_sc + 128, sa_bi + 128, o2, k0, r0, r1);
  *(float4*)&h2[o2][k0] = r0;
  *(float4*)&h2[o2 + 1][k0] = r1;
  __syncthreads();
  layer_f(h2, 128, W3T, sa_sc + 256, sa_bi + 256, o2, k0, r0, r1);
  float m0 = fmaxf(fmaxf(r0.x, r0.y), fmaxf(r0.z, r0.w));
  float m1 = fmaxf(fmaxf(r1.x, r1.y), fmaxf(r1.z, r1.w));
  int w = tid >> 6;
  h1[o2][w] = m0;
  h1[o2 + 1][w] = m1;
  __syncthreads();
  if (tid < 128) {
    float m = fmaxf(fmaxf(h1[tid][0], h1[tid][1]), fmaxf(h1[tid][2], h1[tid][3]));
    feat0[((size_t)b * 128 + tid) * 128 + s] = m;
  }
}

// ---------------- FC heads: (x@Wm + bm)*scale + bias, relu, x2 ----------------
__global__ __launch_bounds__(256) void head_kernel(
    const float* __restrict__ feat0, const float* __restrict__ WmT,
    const float* __restrict__ bm, const float* __restrict__ msc,
    const float* __restrict__ mbi, float* __restrict__ out_feat) {
  int blk = blockIdx.x;
  int b = blk >> 2;
  int sbase = (blk & 3) * 32;
  int tid = threadIdx.x;
  __shared__ float fa[128][36];
  __shared__ float fb[128][36];
  {
    int sj = tid & 31, c0 = tid >> 5;
    for (int c = c0; c < 128; c += 8)
      fa[c][sj] = feat0[((size_t)b * 128 + c) * 128 + sbase + sj];
  }
  __syncthreads();
  int o2 = (tid & 63) * 2, s0 = (tid >> 6) * 8;
  float a0[8], a1[8];
#pragma unroll
  for (int j = 0; j < 8; ++j) { a0[j] = 0.f; a1[j] = 0.f; }
  for (int c = 0; c < 128; ++c) {
    float2 w = *(const float2*)&WmT[c * 128 + o2];
    float4 f0 = *(const float4*)&fa[c][s0];
    float4 f1 = *(const float4*)&fa[c][s0 + 4];
    a0[0] = fmaf(w.x, f0.x, a0[0]); a0[1] = fmaf(w.x, f0.y, a0[1]);
    a0[2] = fmaf(w.x, f0.z, a0[2]); a0[3] = fmaf(w.x, f0.w, a0[3]);
    a0[4] = fmaf(w.x, f1.x, a0[4]); a0[5] = fmaf(w.x, f1.y, a0[5]);
    a0[6] = fmaf(w.x, f1.z, a0[6]); a0[7] = fmaf(w.x, f1.w, a0[7]);
    a1[0] = fmaf(w.y, f0.x, a1[0]); a1[1] = fmaf(w.y, f0.y, a1[1]);
    a1[2] = fmaf(w.y, f0.z, a1[2]); a1[3] = fmaf(w.y, f0.w, a1[3]);
    a1[4] = fmaf(w.y, f1.x, a1[4]); a1[5] = fmaf(w.y, f1.y, a1[5]);
    a1[6] = fmaf(w.y, f1.z, a1[6]); a1[7] = fmaf(w.y, f1.w, a1[7]);
  }
  {
    float c0 = bm[o2], c1 = bm[o2 + 1];
    float t0 = msc[o2], t1 = msc[o2 + 1];
    float q0 = mbi[o2], q1 = mbi[o2 + 1];
#pragma unroll
    for (int j = 0; j < 8; ++j) {
      fb[o2][s0 + j]     = fmaxf(fmaf(a0[j] + c0, t0, q0), 0.f);
      fb[o2 + 1][s0 + j] = fmaxf(fmaf(a1[j] + c1, t1, q1), 0.f);
    }
  }
  __syncthreads();
#pragma unroll
  for (int j = 0; j < 8; ++j) { a0[j] = 0.f; a1[j] = 0.f; }
  for (int c = 0; c < 128; ++c) {
    float2 w = *(const float2*)&WmT[16384 + c * 128 + o2];
    float4 f0 = *(const float4*)&fb[c][s0];
    float4 f1 = *(const float4*)&fb[c][s0 + 4];
    a0[0] = fmaf(w.x, f0.x, a0[0]); a0[1] = fmaf(w.x, f0.y, a0[1]);
    a0[2] = fmaf(w.x, f0.z, a0[2]); a0[3] = fmaf(w.x, f0.w, a0[3]);
    a0[4] = fmaf(w.x, f1.x, a0[4]); a0[5] = fmaf(w.x, f1.y, a0[5]);
    a0[6] = fmaf(w.x, f1.z, a0[6]); a0[7] = fmaf(w.x, f1.w, a0[7]);
    a1[0] = fmaf(w.y, f0.x, a1[0]); a1[1] = fmaf(w.y, f0.y, a1[1]);
    a1[2] = fmaf(w.y, f0.z, a1[2]); a1[3] = fmaf(w.y, f0.w, a1[3]);
    a1[4] = fmaf(w.y, f1.x, a1[4]); a1[5] = fmaf(w.y, f1.y, a1[5]);
    a1[6] = fmaf(w.y, f1.z, a1[6]); a1[7] = fmaf(w.y, f1.w, a1[7]);
  }
  {
    float c0 = bm[128 + o2], c1 = bm[128 + o2 + 1];
    float t0 = msc[128 + o2], t1 = msc[128 + o2 + 1];
    float q0 = mbi[128 + o2], q1 = mbi[128 + o2 + 1];
    float4 v0a, v0b, v1a, v1b;
    v0a.x = fmaxf(fmaf(a0[0] + c0, t0, q0), 0.f);
    v0a.y = fmaxf(fmaf(a0[1] + c0, t0, q0), 0.f);
    v0a.z = fmaxf(fmaf(a0[2] + c0, t0, q0), 0.f);
    v0a.w = fmaxf(fmaf(a0[3] + c0, t0, q0), 0.f);
    v0b.x = fmaxf(fmaf(a0[4] + c0, t0, q0), 0.f);
    v0b.y = fmaxf(fmaf(a0[5] + c0, t0, q0), 0.f);
    v0b.z = fmaxf(fmaf(a0[6] + c0, t0, q0), 0.f);
    v0b.w = fmaxf(fmaf(a0[7] + c0, t0, q0), 0.f);
    v1a.x = fmaxf(fmaf(a1[0] + c1, t1, q1), 0.f);
    v1a.y = fmaxf(fmaf(a1[1] + c1, t1, q1), 0.f);
    v1a.z = fmaxf(fmaf(a1[2] + c1, t1, q1), 0.f);
    v1a.w = fmaxf(fmaf(a1[3] + c1, t1, q1), 0.f);
    v1b.x = fmaxf(fmaf(a1[4] + c1, t1, q1), 0.f);
    v1b.y = fmaxf(fmaf(a1[5] + c1, t1, q1), 0.f);
    v1b.z = fmaxf(fmaf(a1[6] + c1, t1, q1), 0.f);
    v1b.w = fmaxf(fmaf(a1[7] + c1, t1, q1), 0.f);
    float* p0 = &out_feat[((size_t)b * 128 + o2) * 128 + sbase + s0];
    float* p1 = &out_feat[((size_t)b * 128 + o2 + 1) * 128 + sbase + s0];
    *(float4*)p0 = v0a;
    *(float4*)(p0 + 4) = v0b;
    *(float4*)p1 = v1a;
    *(float4*)(p1 + 4) = v1b;
  }
}

extern "C" void kernel_launch(void* const* d_in, const int* in_sizes, int n_in,
                              void* d_out, int out_size, void* d_ws, size_t ws_size,
                              hipStream_t stream) {
  const float* vote_xyz  = (const float*)d_in[0];
  const float* vote_feat = (const float*)d_in[1];
  const float* W1   = (const float*)d_in[2];
  const float* W2   = (const float*)d_in[3];
  const float* W3   = (const float*)d_in[4];
  const float* sasc = (const float*)d_in[5];
  const float* sabi = (const float*)d_in[6];
  const float* Wm   = (const float*)d_in[7];
  const float* bm   = (const float*)d_in[8];
  const float* msc  = (const float*)d_in[9];
  const float* mbi  = (const float*)d_in[10];

  float* out = (float*)d_out;
  float* out_xyz  = out;                    // B*NP*3   = 6144
  float* out_feat = out + 6144;             // B*128*NP = 262144
  float* out_indf = out + 6144 + 262144;    // B*NP     = 2048

  char* ws = (char*)d_ws;
  float* centers = (float*)(ws + 8192);     //  24 KB
  int*   bidx    = (int*)(ws + 32768);      // 128 KB
  float* W1T     = (float*)(ws + 163840);   // 132608 B
  float* W2T     = (float*)(ws + 296448);   //  64 KB
  float* W3T     = (float*)(ws + 361984);   //  64 KB
  float* WmT     = (float*)(ws + 427520);   // 128 KB
  float* feat0   = (float*)(ws + 558592);   //   1 MB

  hipLaunchKernelGGL(transpose_kernel, dim3(130), dim3(256), 0, stream,
                     W1, W2, W3, Wm, W1T, W2T, W3T, WmT);
  hipLaunchKernelGGL(fps_kernel, dim3(NB), dim3(FTH), 0, stream,
                     vote_xyz, centers, out_xyz, out_indf);
  hipLaunchKernelGGL(ballq_kernel, dim3(NB * NPP), dim3(64), 0, stream,
                     vote_xyz, centers, bidx);
  hipLaunchKernelGGL(mlp_kernel, dim3(NB * NPP), dim3(256), 0, stream,
                     vote_xyz, vote_feat, centers, bidx, W1T, W2T, W3T,
                     sasc, sabi, feat0);
  hipLaunchKernelGGL(head_kernel, dim3(NB * 4), dim3(256), 0, stream,
                     feat0, WmT, bm, msc, mbi, out_feat);
}

// Round 8
// 403.966 us; speedup vs baseline: 1.0659x; 1.0160x over previous
//
#include <hip/hip_runtime.h>
#include <hip/hip_bf16.h>

#define NB  16
#define NN  16384
#define NC  256
#define NPP 128
#define NSS 16

#define FTH 1024  // fps threads per block (16 waves = 4 waves/SIMD)
#define FPT 16    // fps points per thread

// ---------------- weight transpose (one-shot, tiny) ----------------
__global__ __launch_bounds__(256) void transpose_kernel(
    const float* __restrict__ W1, const float* __restrict__ W2,
    const float* __restrict__ W3, const float* __restrict__ Wm,
    float* __restrict__ W1T, float* __restrict__ W2T,
    float* __restrict__ W3T, float* __restrict__ WmT) {
  int i = blockIdx.x * 256 + threadIdx.x;
  if (i < 128 * 259) { int o = i / 259, c = i - o * 259; W1T[c * 128 + o] = W1[i]; }
  if (i < 128 * 128) {
    int o = i >> 7, c = i & 127;
    W2T[c * 128 + o] = W2[i];
    W3T[c * 128 + o] = W3[i];
    WmT[c * 128 + o] = Wm[i];
    WmT[16384 + c * 128 + o] = Wm[16384 + i];
  }
}

// ---------------- FPS: one block per batch ----------------
// Exact numpy semantics: d = ((dx*dx + dy*dy) + dz*dz), per-op rounding,
// argmax tie-break = lowest index via packed u64 max:
//   pack = (f32bits(val) << 32) | ~idx
// STATE SPLIT (rounds 2-7 lesson: allocator refuses >~52 VGPRs and spills
// any >=64-float per-thread state -> all variants spill-bound ~1.8us/iter):
//   (x,y) -> LDS, 16384*8B = 128KB, one ds_read_b64/pt/iter (~6cyc, own pipe)
//   z, MD -> registers, only 32 floats/thread (allocator keeps these)
// 128KB LDS also caps occupancy at 1 WG/CU -> compiler budgets 128 VGPRs.
// Per-CU per-iter: LDS ~1536cyc || VALU ~1536cyc (overlap) + ~400 tail.
__global__ __attribute__((amdgpu_flat_work_group_size(1024, 1024),
                          amdgpu_waves_per_eu(4, 4)))
void fps_kernel(
    const float* __restrict__ xyz,
    float* __restrict__ centers, float* __restrict__ out_xyz,
    float* __restrict__ out_indf) {
  int b = blockIdx.x;
  const float* px = xyz + (size_t)b * (NN * 3);
  int t = threadIdx.x;
  __shared__ float2 sxy[NN];                  // 128 KB
  __shared__ unsigned long long cand[2][16];
  float Zr[FPT], MD[FPT];
#pragma unroll
  for (int j = 0; j < FPT; ++j) {
    int n = t + j * FTH;
    float x = px[n * 3 + 0];
    float y = px[n * 3 + 1];
    float z = px[n * 3 + 2];
    asm volatile("" : "+v"(z));   // z must stay in a reg, not be re-loaded
    sxy[n] = make_float2(x, y);
    Zr[j] = z;
    MD[j] = 1e10f;
  }
  float cx = px[0], cy = px[1], cz = px[2];
  if (t == 0) {
    out_indf[b * NPP] = 0.0f;
    centers[(b * NPP) * 3 + 0] = cx;
    centers[(b * NPP) * 3 + 1] = cy;
    centers[(b * NPP) * 3 + 2] = cz;
    out_xyz[(b * NPP) * 3 + 0] = cx;
    out_xyz[(b * NPP) * 3 + 1] = cy;
    out_xyz[(b * NPP) * 3 + 2] = cz;
  }
  __syncthreads();
  for (int it = 1; it < NPP; ++it) {
    float bv = -1.0f;
    int bj = 0;
#pragma unroll
    for (int j = 0; j < FPT; ++j) {
      float2 v = sxy[t + j * FTH];
      float dx = __fsub_rn(v.x, cx);
      float dy = __fsub_rn(v.y, cy);
      float dz = __fsub_rn(Zr[j], cz);
      float d  = __fadd_rn(__fadd_rn(__fmul_rn(dx, dx), __fmul_rn(dy, dy)),
                           __fmul_rn(dz, dz));
      float m = fminf(MD[j], d);
      MD[j] = m;
      if (m > bv) { bv = m; bj = j; }  // strict > keeps lowest j (first occ.)
    }
    int bi = t + bj * FTH;
    unsigned long long pk =
        (((unsigned long long)__float_as_uint(bv)) << 32) |
        (unsigned long long)(~(unsigned)bi);
    // ---- wave64 max-reduce: 4x DPP row_ror + swizzle xor16 + shfl xor32 --
#define STEP_ROR(N)                                                         \
    {                                                                       \
      unsigned lo = (unsigned)pk, hi = (unsigned)(pk >> 32);                \
      lo = (unsigned)__builtin_amdgcn_mov_dpp((int)lo, 0x120 | N, 0xF, 0xF, true); \
      hi = (unsigned)__builtin_amdgcn_mov_dpp((int)hi, 0x120 | N, 0xF, 0xF, true); \
      unsigned long long o = ((unsigned long long)hi << 32) | lo;           \
      if (o > pk) pk = o;                                                   \
    }
    STEP_ROR(1) STEP_ROR(2) STEP_ROR(4) STEP_ROR(8)
    {  // lane ^ 16 within 32-lane halves (ds_swizzle BitMode 0x401F)
      unsigned lo = (unsigned)pk, hi = (unsigned)(pk >> 32);
      lo = (unsigned)__builtin_amdgcn_ds_swizzle((int)lo, 0x401F);
      hi = (unsigned)__builtin_amdgcn_ds_swizzle((int)hi, 0x401F);
      unsigned long long o = ((unsigned long long)hi << 32) | lo;
      if (o > pk) pk = o;
    }
    {  // lane ^ 32
      unsigned long long o = __shfl_xor(pk, 32, 64);
      if (o > pk) pk = o;
    }
    if ((t & 63) == 0) cand[it & 1][t >> 6] = pk;
    __syncthreads();
    // ---- 16-candidate combine: broadcast read + 4 DPP row_ror steps ----
    pk = cand[it & 1][t & 15];
    STEP_ROR(1) STEP_ROR(2) STEP_ROR(4) STEP_ROR(8)
#undef STEP_ROR
    int win = (int)(~(unsigned)(pk & 0xFFFFFFFFull));
    win = __builtin_amdgcn_readfirstlane(win);
    float2 wv = sxy[win];          // uniform LDS read (broadcast, free-ish)
    cx = wv.x;
    cy = wv.y;
    cz = px[win * 3 + 2];          // uniform global read (L2-resident)
    if (t == 0) {
      out_indf[b * NPP + it] = (float)win;
      centers[(b * NPP + it) * 3 + 0] = cx;
      centers[(b * NPP + it) * 3 + 1] = cy;
      centers[(b * NPP + it) * 3 + 2] = cz;
      out_xyz[(b * NPP + it) * 3 + 0] = cx;
      out_xyz[(b * NPP + it) * 3 + 1] = cy;
      out_xyz[(b * NPP + it) * 3 + 2] = cz;
    }
  }
}

// ---------------- ball query: one wave per (b, center) ----------------
__global__ __launch_bounds__(64) void ballq_kernel(
    const float* __restrict__ xyz, const float* __restrict__ centers,
    int* __restrict__ bidx) {
  int bs = blockIdx.x;  // b*128 + s
  int b = bs >> 7;
  int lane = threadIdx.x;
  const float* px = xyz + (size_t)b * (NN * 3);
  float cx = centers[bs * 3 + 0];
  float cy = centers[bs * 3 + 1];
  float cz = centers[bs * 3 + 2];
  __shared__ int coll[NSS];
  const float rr = 0.09f;  // f32(0.09): identical membership to f64 compare
  int have = 0;
  for (int c0 = 0; c0 < NN; c0 += 64) {
    int n = c0 + lane;
    float dx = __fsub_rn(px[n * 3 + 0], cx);
    float dy = __fsub_rn(px[n * 3 + 1], cy);
    float dz = __fsub_rn(px[n * 3 + 2], cz);
    float d2 = __fadd_rn(__fadd_rn(__fmul_rn(dx, dx), __fmul_rn(dy, dy)),
                         __fmul_rn(dz, dz));
    bool in = d2 < rr;
    unsigned long long m = __ballot(in);
    if (in) {
      int pos = have + __popcll(m & ((1ull << lane) - 1ull));
      if (pos < NSS) coll[pos] = n;
    }
    have += __popcll(m);
    if (have >= NSS) break;
  }
  __syncthreads();
  int first = coll[0];
  if (lane < NSS) bidx[bs * NSS + lane] = (lane < have) ? coll[lane] : first;
}

// ---------------- grouped MLP (3 layers + maxpool over NS) ----------------
__device__ __forceinline__ void layer_f(const float (*in)[20], int cin,
                                        const float* __restrict__ WT,
                                        const float* __restrict__ sc,
                                        const float* __restrict__ bi,
                                        int o2, int k0, float4& r0, float4& r1) {
  float a0[4] = {0.f, 0.f, 0.f, 0.f};
  float a1[4] = {0.f, 0.f, 0.f, 0.f};
  for (int c = 0; c < cin; ++c) {
    float2 w = *(const float2*)(WT + c * 128 + o2);
    float4 gv = *(const float4*)(&in[c][k0]);
    a0[0] = fmaf(w.x, gv.x, a0[0]);
    a0[1] = fmaf(w.x, gv.y, a0[1]);
    a0[2] = fmaf(w.x, gv.z, a0[2]);
    a0[3] = fmaf(w.x, gv.w, a0[3]);
    a1[0] = fmaf(w.y, gv.x, a1[0]);
    a1[1] = fmaf(w.y, gv.y, a1[1]);
    a1[2] = fmaf(w.y, gv.z, a1[2]);
    a1[3] = fmaf(w.y, gv.w, a1[3]);
  }
  float s0 = sc[o2], s1 = sc[o2 + 1], b0 = bi[o2], b1 = bi[o2 + 1];
  r0.x = fmaxf(fmaf(a0[0], s0, b0), 0.f);
  r0.y = fmaxf(fmaf(a0[1], s0, b0), 0.f);
  r0.z = fmaxf(fmaf(a0[2], s0, b0), 0.f);
  r0.w = fmaxf(fmaf(a0[3], s0, b0), 0.f);
  r1.x = fmaxf(fmaf(a1[0], s1, b1), 0.f);
  r1.y = fmaxf(fmaf(a1[1], s1, b1), 0.f);
  r1.z = fmaxf(fmaf(a1[2], s1, b1), 0.f);
  r1.w = fmaxf(fmaf(a1[3], s1, b1), 0.f);
}

__global__ __launch_bounds__(256) void mlp_kernel(
    const float* __restrict__ xyz, const float* __restrict__ feats,
    const float* __restrict__ centers, const int* __restrict__ bidx,
    const float* __restrict__ W1T, const float* __restrict__ W2T,
    const float* __restrict__ W3T, const float* __restrict__ sa_sc,
    const float* __restrict__ sa_bi, float* __restrict__ feat0) {
  int bs = blockIdx.x;
  int b = bs >> 7;
  int s = bs & 127;
  int tid = threadIdx.x;
  __shared__ float g[259][20];
  __shared__ float h1[128][20];
  __shared__ float h2[128][20];
  __shared__ int kidx[NSS];
  __shared__ float ctr[3];
  if (tid < NSS) kidx[tid] = bidx[bs * NSS + tid];
  if (tid < 3) ctr[tid] = centers[bs * 3 + tid];
  __syncthreads();
  const float* px = xyz + (size_t)b * (NN * 3);
  if (tid < NSS) {
    int n = kidx[tid];
    g[0][tid] = __fdiv_rn(__fsub_rn(px[n * 3 + 0], ctr[0]), 0.3f);
    g[1][tid] = __fdiv_rn(__fsub_rn(px[n * 3 + 1], ctr[1]), 0.3f);
    g[2][tid] = __fdiv_rn(__fsub_rn(px[n * 3 + 2], ctr[2]), 0.3f);
  }
  {
    const float* row = feats + ((size_t)b * NC + tid) * NN;
#pragma unroll
    for (int k = 0; k < NSS; ++k) g[3 + tid][k] = row[kidx[k]];
  }
  __syncthreads();
  int o2 = (tid & 63) * 2;
  int k0 = (tid >> 6) * 4;
  float4 r0, r1;
  layer_f(g, 259, W1T, sa_sc, sa_bi, o2, k0, r0, r1);
  *(float4*)&h1[o2][k0] = r0;
  *(float4*)&h1[o2 + 1][k0] = r1;
  __syncthreads();
  layer_f(h1, 128, W2T, sa_sc + 128, sa_bi + 128, o2, k0, r0, r1);
  *(float4*)&h2[o2][k0] = r0;
  *(float4*)&h2[o2 + 1][k0] = r1;
  __syncthreads();
  layer_f(h2, 128, W3T, sa_sc + 256, sa_bi + 256, o2, k0, r0, r1);
  float m0 = fmaxf(fmaxf(r0.x, r0.y), fmaxf(r0.z, r0.w));
  float m1 = fmaxf(fmaxf(r1.x, r1.y), fmaxf(r1.z, r1.w));
  int w = tid >> 6;
  h1[o2][w] = m0;
  h1[o2 + 1][w] = m1;
  __syncthreads();
  if (tid < 128) {
    float m = fmaxf(fmaxf(h1[tid][0], h1[tid][1]), fmaxf(h1[tid][2], h1[tid][3]));
    feat0[((size_t)b * 128 + tid) * 128 + s] = m;
  }
}

// ---------------- FC heads: (x@Wm + bm)*scale + bias, relu, x2 ----------------
__global__ __launch_bounds__(256) void head_kernel(
    const float* __restrict__ feat0, const float* __restrict__ WmT,
    const float* __restrict__ bm, const float* __restrict__ msc,
    const float* __restrict__ mbi, float* __restrict__ out_feat) {
  int blk = blockIdx.x;
  int b = blk >> 2;
  int sbase = (blk & 3) * 32;
  int tid = threadIdx.x;
  __shared__ float fa[128][36];
  __shared__ float fb[128][36];
  {
    int sj = tid & 31, c0 = tid >> 5;
    for (int c = c0; c < 128; c += 8)
      fa[c][sj] = feat0[((size_t)b * 128 + c) * 128 + sbase + sj];
  }
  __syncthreads();
  int o2 = (tid & 63) * 2, s0 = (tid >> 6) * 8;
  float a0[8], a1[8];
#pragma unroll
  for (int j = 0; j < 8; ++j) { a0[j] = 0.f; a1[j] = 0.f; }
  for (int c = 0; c < 128; ++c) {
    float2 w = *(const float2*)&WmT[c * 128 + o2];
    float4 f0 = *(const float4*)&fa[c][s0];
    float4 f1 = *(const float4*)&fa[c][s0 + 4];
    a0[0] = fmaf(w.x, f0.x, a0[0]); a0[1] = fmaf(w.x, f0.y, a0[1]);
    a0[2] = fmaf(w.x, f0.z, a0[2]); a0[3] = fmaf(w.x, f0.w, a0[3]);
    a0[4] = fmaf(w.x, f1.x, a0[4]); a0[5] = fmaf(w.x, f1.y, a0[5]);
    a0[6] = fmaf(w.x, f1.z, a0[6]); a0[7] = fmaf(w.x, f1.w, a0[7]);
    a1[0] = fmaf(w.y, f0.x, a1[0]); a1[1] = fmaf(w.y, f0.y, a1[1]);
    a1[2] = fmaf(w.y, f0.z, a1[2]); a1[3] = fmaf(w.y, f0.w, a1[3]);
    a1[4] = fmaf(w.y, f1.x, a1[4]); a1[5] = fmaf(w.y, f1.y, a1[5]);
    a1[6] = fmaf(w.y, f1.z, a1[6]); a1[7] = fmaf(w.y, f1.w, a1[7]);
  }
  {
    float c0 = bm[o2], c1 = bm[o2 + 1];
    float t0 = msc[o2], t1 = msc[o2 + 1];
    float q0 = mbi[o2], q1 = mbi[o2 + 1];
#pragma unroll
    for (int j = 0; j < 8; ++j) {
      fb[o2][s0 + j]     = fmaxf(fmaf(a0[j] + c0, t0, q0), 0.f);
      fb[o2 + 1][s0 + j] = fmaxf(fmaf(a1[j] + c1, t1, q1), 0.f);
    }
  }
  __syncthreads();
#pragma unroll
  for (int j = 0; j < 8; ++j) { a0[j] = 0.f; a1[j] = 0.f; }
  for (int c = 0; c < 128; ++c) {
    float2 w = *(const float2*)&WmT[16384 + c * 128 + o2];
    float4 f0 = *(const float4*)&fb[c][s0];
    float4 f1 = *(const float4*)&fb[c][s0 + 4];
    a0[0] = fmaf(w.x, f0.x, a0[0]); a0[1] = fmaf(w.x, f0.y, a0[1]);
    a0[2] = fmaf(w.x, f0.z, a0[2]); a0[3] = fmaf(w.x, f0.w, a0[3]);
    a0[4] = fmaf(w.x, f1.x, a0[4]); a0[5] = fmaf(w.x, f1.y, a0[5]);
    a0[6] = fmaf(w.x, f1.z, a0[6]); a0[7] = fmaf(w.x, f1.w, a0[7]);
    a1[0] = fmaf(w.y, f0.x, a1[0]); a1[1] = fmaf(w.y, f0.y, a1[1]);
    a1[2] = fmaf(w.y, f0.z, a1[2]); a1[3] = fmaf(w.y, f0.w, a1[3]);
    a1[4] = fmaf(w.y, f1.x, a1[4]); a1[5] = fmaf(w.y, f1.y, a1[5]);
    a1[6] = fmaf(w.y, f1.z, a1[6]); a1[7] = fmaf(w.y, f1.w, a1[7]);
  }
  {
    float c0 = bm[128 + o2], c1 = bm[128 + o2 + 1];
    float t0 = msc[128 + o2], t1 = msc[128 + o2 + 1];
    float q0 = mbi[128 + o2], q1 = mbi[128 + o2 + 1];
    float4 v0a, v0b, v1a, v1b;
    v0a.x = fmaxf(fmaf(a0[0] + c0, t0, q0), 0.f);
    v0a.y = fmaxf(fmaf(a0[1] + c0, t0, q0), 0.f);
    v0a.z = fmaxf(fmaf(a0[2] + c0, t0, q0), 0.f);
    v0a.w = fmaxf(fmaf(a0[3] + c0, t0, q0), 0.f);
    v0b.x = fmaxf(fmaf(a0[4] + c0, t0, q0), 0.f);
    v0b.y = fmaxf(fmaf(a0[5] + c0, t0, q0), 0.f);
    v0b.z = fmaxf(fmaf(a0[6] + c0, t0, q0), 0.f);
    v0b.w = fmaxf(fmaf(a0[7] + c0, t0, q0), 0.f);
    v1a.x = fmaxf(fmaf(a1[0] + c1, t1, q1), 0.f);
    v1a.y = fmaxf(fmaf(a1[1] + c1, t1, q1), 0.f);
    v1a.z = fmaxf(fmaf(a1[2] + c1, t1, q1), 0.f);
    v1a.w = fmaxf(fmaf(a1[3] + c1, t1, q1), 0.f);
    v1b.x = fmaxf(fmaf(a1[4] + c1, t1, q1), 0.f);
    v1b.y = fmaxf(fmaf(a1[5] + c1, t1, q1), 0.f);
    v1b.z = fmaxf(fmaf(a1[6] + c1, t1, q1), 0.f);
    v1b.w = fmaxf(fmaf(a1[7] + c1, t1, q1), 0.f);
    float* p0 = &out_feat[((size_t)b * 128 + o2) * 128 + sbase + s0];
    float* p1 = &out_feat[((size_t)b * 128 + o2 + 1) * 128 + sbase + s0];
    *(float4*)p0 = v0a;
    *(float4*)(p0 + 4) = v0b;
    *(float4*)p1 = v1a;
    *(float4*)(p1 + 4) = v1b;
  }
}

extern "C" void kernel_launch(void* const* d_in, const int* in_sizes, int n_in,
                              void* d_out, int out_size, void* d_ws, size_t ws_size,
                              hipStream_t stream) {
  const float* vote_xyz  = (const float*)d_in[0];
  const float* vote_feat = (const float*)d_in[1];
  const float* W1   = (const float*)d_in[2];
  const float* W2   = (const float*)d_in[3];
  const float* W3   = (const float*)d_in[4];
  const float* sasc = (const float*)d_in[5];
  const float* sabi = (const float*)d_in[6];
  const float* Wm   = (const float*)d_in[7];
  const float* bm   = (const float*)d_in[8];
  const float* msc  = (const float*)d_in[9];
  const float* mbi  = (const float*)d_in[10];

  float* out = (float*)d_out;
  float* out_xyz  = out;                    // B*NP*3   = 6144
  float* out_feat = out + 6144;             // B*128*NP = 262144
  float* out_indf = out + 6144 + 262144;    // B*NP     = 2048

  char* ws = (char*)d_ws;
  float* centers = (float*)(ws + 8192);     //  24 KB
  int*   bidx    = (int*)(ws + 32768);      // 128 KB
  float* W1T     = (float*)(ws + 163840);   // 132608 B
  float* W2T     = (float*)(ws + 296448);   //  64 KB
  float* W3T     = (float*)(ws + 361984);   //  64 KB
  float* WmT     = (float*)(ws + 427520);   // 128 KB
  float* feat0   = (float*)(ws + 558592);   //   1 MB

  hipLaunchKernelGGL(transpose_kernel, dim3(130), dim3(256), 0, stream,
                     W1, W2, W3, Wm, W1T, W2T, W3T, WmT);
  hipLaunchKernelGGL(fps_kernel, dim3(NB), dim3(FTH), 0, stream,
                     vote_xyz, centers, out_xyz, out_indf);
  hipLaunchKernelGGL(ballq_kernel, dim3(NB * NPP), dim3(64), 0, stream,
                     vote_xyz, centers, bidx);
  hipLaunchKernelGGL(mlp_kernel, dim3(NB * NPP), dim3(256), 0, stream,
                     vote_xyz, vote_feat, centers, bidx, W1T, W2T, W3T,
                     sasc, sabi, feat0);
  hipLaunchKernelGGL(head_kernel, dim3(NB * 4), dim3(256), 0, stream,
                     feat0, WmT, bm, msc, mbi, out_feat);
}